// Round 1
// baseline (74.644 us; speedup 1.0000x reference)
//
#include <hip/hip_runtime.h>

// Symmetrization net, closed form:
//   out[j,c] = 8! * (sum_h hsum[h]*W2[h,c] + 9*b2[c])   (independent of j)
//   hsum[h]  = sum_i relu((x@W1)[i,h] + b1[h])
// Perms table never read.
//
// R2 analysis: rocprof showed the timed window dominated by the harness's
// 256 MiB d_ws poison fill (41.4 us @ 81% HBM peak). Old kernel A *read and
// wrote d_ws*, so the graph serialized fill -> A -> B (~70 us). Fix: never
// touch d_ws. Single-block single-launch kernel; all 83 KB of input loads are
// issued as one independent batch across 1024 threads (32 d-chunks x 32 h),
// then three cheap LDS reduce phases. No workspace, no atomics, one dispatch.

#define NROWS 9
#define DDIM  512
#define HDIM  32
#define OUTC  4
#define NCH   32                 // d-chunks
#define DCH   (DDIM / NCH)       // 16 d-values per chunk
#define NTHR  (NCH * HDIM)       // 1024 threads
#define FACT8 40320.0f           // 8!

__global__ __launch_bounds__(NTHR)
void sym_all_kernel(const float* __restrict__ x,
                    const float* __restrict__ W1,
                    const float* __restrict__ b1,
                    const float* __restrict__ W2,
                    const float* __restrict__ b2,
                    float* __restrict__ out)
{
    // part[i][c][h]: addr = i*1024 + c*32 + h floats -> within a wave
    // (2 chunks x 32 h) lanes map to banks h with 2-way aliasing: free.
    __shared__ float part[NROWS][NCH][HDIM];   // 36 KB
    __shared__ float hbuf[NROWS][HDIM];
    __shared__ float hsum[HDIM];

    const int t  = threadIdx.x;      // 0..1023
    const int h  = t & 31;           // hidden unit
    const int c0 = t >> 5;           // d-chunk 0..31
    const int d0 = c0 * DCH;

    // ---- Phase 1: partial pre-activations over this thread's d-slice ------
    // 16 W1 loads (coalesced across h: consecutive 32 floats per d) and
    // 9 x 4 float4 x-loads (broadcast across the 32 h-lanes of a chunk).
    // All loads independent -> single vmcnt latency exposure.
    float w[DCH];
#pragma unroll
    for (int k = 0; k < DCH; ++k) w[k] = W1[(d0 + k) * HDIM + h];

#pragma unroll
    for (int i = 0; i < NROWS; ++i) {
        const float4* x4 = (const float4*)(x + i * DDIM + d0);  // d0%16==0 -> aligned
        float acc = 0.f;
#pragma unroll
        for (int q = 0; q < DCH / 4; ++q) {
            const float4 v = x4[q];
            acc += (v.x * w[4*q+0] + v.y * w[4*q+1])
                 + (v.z * w[4*q+2] + v.w * w[4*q+3]);
        }
        part[i][c0][h] = acc;
    }
    __syncthreads();

    // ---- Phase 2: reduce 32 chunk-partials, bias + relu --------------------
    if (t < NROWS * HDIM) {
        const int i = t >> 5;        // row; h = t & 31 (reuse)
        float s0 = 0.f, s1 = 0.f, s2 = 0.f, s3 = 0.f;
#pragma unroll
        for (int cc = 0; cc < NCH; cc += 4) {
            s0 += part[i][cc + 0][h];
            s1 += part[i][cc + 1][h];
            s2 += part[i][cc + 2][h];
            s3 += part[i][cc + 3][h];
        }
        const float hv = (s0 + s1) + (s2 + s3) + b1[h];
        hbuf[i][h] = hv > 0.f ? hv : 0.f;
    }
    __syncthreads();

    // ---- Phase 3: sum over rows -------------------------------------------
    if (t < HDIM) {
        float s = 0.f;
#pragma unroll
        for (int r = 0; r < NROWS; ++r) s += hbuf[r][t];
        hsum[t] = s;
    }
    __syncthreads();

    // ---- Phase 4: W2 matvec + bias, broadcast to all 9 output rows --------
    if (t < NROWS * OUTC) {
        const int c = t & 3;
        float s = 0.f;
#pragma unroll
        for (int hh = 0; hh < HDIM; ++hh) s += hsum[hh] * W2[hh * OUTC + c];
        out[t] = FACT8 * (s + (float)NROWS * b2[c]);
    }
}

extern "C" void kernel_launch(void* const* d_in, const int* in_sizes, int n_in,
                              void* d_out, int out_size, void* d_ws, size_t ws_size,
                              hipStream_t stream)
{
    const float* x  = (const float*)d_in[0];   // [9, 512]
    const float* W1 = (const float*)d_in[1];   // [512, 32]
    const float* b1 = (const float*)d_in[2];   // [32]
    const float* W2 = (const float*)d_in[3];   // [32, 4]
    const float* b2 = (const float*)d_in[4];   // [4]
    // d_in[5] = perms [362880, 9] — mathematically unused (closed form).
    float* out = (float*)d_out;                // [9, 4]
    // d_ws deliberately untouched: its 256 MiB poison fill dominates the timed
    // graph; any use of it serializes our kernels behind that fill.

    sym_all_kernel<<<1, NTHR, 0, stream>>>(x, W1, b1, W2, b2, out);
}